// Round 1
// baseline (24422.240 us; speedup 1.0000x reference)
//
#include <hip/hip_runtime.h>
#include <hip/hip_bf16.h>

#define USER_N   100000
#define ITEM_N   200000
#define N_NODES  300000           // USER_N + ITEM_N
#define LATDIM   64
#define N_EDGES  9600000
#define N_LAYERS 3

// ---------------------------------------------------------------------------
// copy concat(u, i) -> cur (ws) and acc (d_out), float4-vectorized
// ---------------------------------------------------------------------------
__global__ void copy_concat_kernel(const float* __restrict__ u,
                                   const float* __restrict__ it,
                                   float* __restrict__ cur,
                                   float* __restrict__ acc,
                                   int n4u, int n4total) {
    int stride = gridDim.x * blockDim.x;
    for (int i = blockIdx.x * blockDim.x + threadIdx.x; i < n4total; i += stride) {
        float4 v = (i < n4u) ? ((const float4*)u)[i]
                             : ((const float4*)it)[i - n4u];
        ((float4*)cur)[i] = v;
        ((float4*)acc)[i] = v;
    }
}

// ---------------------------------------------------------------------------
// COO SpMM: y[row[e], :] += val[e] * x[col[e], :]
// 16 lanes per edge, each lane does 4 dims via float4 gather + 4 atomicAdds.
// ---------------------------------------------------------------------------
__global__ void spmm_atomic_kernel(const int*   __restrict__ row,
                                   const int*   __restrict__ col,
                                   const float* __restrict__ val,
                                   const float* __restrict__ x,
                                   float*       __restrict__ y) {
    const int total = N_EDGES * 16;           // 153.6M, fits int32
    int stride = gridDim.x * blockDim.x;
    for (int t = blockIdx.x * blockDim.x + threadIdx.x; t < total; t += stride) {
        int e = t >> 4;
        int q = t & 15;
        int r = row[e];
        int c = col[e];
        float v = val[e];
        float4 g = ((const float4*)x)[c * 16 + q];   // coalesced 256B per edge
        float* yp = y + r * 64 + q * 4;
        atomicAdd(yp + 0, g.x * v);
        atomicAdd(yp + 1, g.y * v);
        atomicAdd(yp + 2, g.z * v);
        atomicAdd(yp + 3, g.w * v);
    }
}

// ---------------------------------------------------------------------------
// acc += layer   (float4-vectorized grid-stride)
// ---------------------------------------------------------------------------
__global__ void acc_add_kernel(float* __restrict__ acc,
                               const float* __restrict__ add,
                               int n4) {
    int stride = gridDim.x * blockDim.x;
    for (int i = blockIdx.x * blockDim.x + threadIdx.x; i < n4; i += stride) {
        float4 a = ((const float4*)acc)[i];
        float4 b = ((const float4*)add)[i];
        a.x += b.x; a.y += b.y; a.z += b.z; a.w += b.w;
        ((float4*)acc)[i] = a;
    }
}

extern "C" void kernel_launch(void* const* d_in, const int* in_sizes, int n_in,
                              void* d_out, int out_size, void* d_ws, size_t ws_size,
                              hipStream_t stream) {
    const float* uEmb = (const float*)d_in[0];
    const float* iEmb = (const float*)d_in[1];
    const int*   row  = (const int*)  d_in[2];
    const int*   col  = (const int*)  d_in[3];
    const float* val  = (const float*)d_in[4];

    float* acc = (float*)d_out;                       // [N, 64] accumulated output
    float* ws0 = (float*)d_ws;                        // cur
    float* ws1 = ws0 + (size_t)N_NODES * LATDIM;      // next

    const int n4total = N_NODES * (LATDIM / 4);       // 4.8M float4
    const int n4u     = USER_N  * (LATDIM / 4);
    const size_t bufBytes = (size_t)N_NODES * LATDIM * sizeof(float);

    const int BLK = 256;
    const int GRID_MEM = 2048;    // grid-stride cap: 8 blocks/CU * 256 CUs
    const int GRID_SPMM = 4096;

    // acc = cur = concat(u, i)
    copy_concat_kernel<<<GRID_MEM, BLK, 0, stream>>>(uEmb, iEmb, ws0, acc,
                                                     n4u, n4total);

    float* cur = ws0;
    float* nxt = ws1;
    for (int l = 0; l < N_LAYERS; ++l) {
        hipMemsetAsync(nxt, 0, bufBytes, stream);
        spmm_atomic_kernel<<<GRID_SPMM, BLK, 0, stream>>>(row, col, val, cur, nxt);
        acc_add_kernel<<<GRID_MEM, BLK, 0, stream>>>(acc, nxt, n4total);
        float* t = cur; cur = nxt; nxt = t;
    }
}

// Round 2
// 2100.233 us; speedup vs baseline: 11.6283x; 11.6283x over previous
//
#include <hip/hip_runtime.h>
#include <hip/hip_bf16.h>

#define USER_N   100000
#define ITEM_N   200000
#define N_NODES  300000           // USER_N + ITEM_N
#define LATDIM   64
#define N_EDGES  9600000
#define N_LAYERS 3

#define SCAN_CHUNK 512
#define N_CHUNKS   ((N_NODES + SCAN_CHUNK - 1) / SCAN_CHUNK)   // 586

// ---------------------------------------------------------------------------
// copy concat(u, i) -> cur (ws) and acc (d_out), float4-vectorized
// ---------------------------------------------------------------------------
__global__ void copy_concat_kernel(const float* __restrict__ u,
                                   const float* __restrict__ it,
                                   float* __restrict__ cur,
                                   float* __restrict__ acc,
                                   int n4u, int n4total) {
    int stride = gridDim.x * blockDim.x;
    for (int i = blockIdx.x * blockDim.x + threadIdx.x; i < n4total; i += stride) {
        float4 v = (i < n4u) ? ((const float4*)u)[i]
                             : ((const float4*)it)[i - n4u];
        ((float4*)cur)[i] = v;
        ((float4*)acc)[i] = v;
    }
}

// ---------------------------------------------------------------------------
// CSR build step 1: histogram of rows
// ---------------------------------------------------------------------------
__global__ void hist_kernel(const int* __restrict__ row, int* __restrict__ counts) {
    int stride = gridDim.x * blockDim.x;
    for (int e = blockIdx.x * blockDim.x + threadIdx.x; e < N_EDGES; e += stride)
        atomicAdd(&counts[row[e]], 1);
}

// ---------------------------------------------------------------------------
// CSR build step 2a: per-chunk sums (chunk = 512 counts, block = 256)
// ---------------------------------------------------------------------------
__global__ void chunk_sum_kernel(const int* __restrict__ counts,
                                 int* __restrict__ chunkSums) {
    __shared__ int lds[256];
    int c = blockIdx.x;
    int t = threadIdx.x;
    int base = c * SCAN_CHUNK;
    int s = 0;
    int i0 = base + t;        if (i0 < N_NODES) s += counts[i0];
    int i1 = base + 256 + t;  if (i1 < N_NODES) s += counts[i1];
    lds[t] = s;
    __syncthreads();
    for (int off = 128; off > 0; off >>= 1) {
        if (t < off) lds[t] += lds[t + off];
        __syncthreads();
    }
    if (t == 0) chunkSums[c] = lds[0];
}

// ---------------------------------------------------------------------------
// CSR build step 2b: exclusive scan of chunk sums (single block, 1024 thr)
// also writes row_ptr[N_NODES] = total edge count
// ---------------------------------------------------------------------------
__global__ void scan_chunks_kernel(const int* __restrict__ chunkSums,
                                   int* __restrict__ chunkOffs,
                                   int* __restrict__ rowPtrLast) {
    __shared__ int lds[1024];
    int t = threadIdx.x;
    int v = (t < N_CHUNKS) ? chunkSums[t] : 0;
    lds[t] = v;
    __syncthreads();
    for (int off = 1; off < 1024; off <<= 1) {
        int add = (t >= off) ? lds[t - off] : 0;
        __syncthreads();
        lds[t] += add;
        __syncthreads();
    }
    if (t < N_CHUNKS) chunkOffs[t] = lds[t] - v;      // exclusive
    if (t == N_CHUNKS - 1) *rowPtrLast = lds[t];      // total = N_EDGES
}

// ---------------------------------------------------------------------------
// CSR build step 2c: scan within chunk (block = 512), writes row_ptr + cursor
// ---------------------------------------------------------------------------
__global__ void scan_within_kernel(const int* __restrict__ counts,
                                   const int* __restrict__ chunkOffs,
                                   int* __restrict__ rowPtr,
                                   int* __restrict__ cursor) {
    __shared__ int lds[SCAN_CHUNK];
    int c = blockIdx.x;
    int t = threadIdx.x;                  // blockDim = 512
    int idx = c * SCAN_CHUNK + t;
    int v = (idx < N_NODES) ? counts[idx] : 0;
    lds[t] = v;
    __syncthreads();
    for (int off = 1; off < SCAN_CHUNK; off <<= 1) {
        int add = (t >= off) ? lds[t - off] : 0;
        __syncthreads();
        lds[t] += add;
        __syncthreads();
    }
    if (idx < N_NODES) {
        int ex = chunkOffs[c] + lds[t] - v;           // exclusive prefix
        rowPtr[idx] = ex;
        cursor[idx] = ex;
    }
}

// ---------------------------------------------------------------------------
// CSR build step 3: scatter edges into row-sorted (col,val) pairs
// ---------------------------------------------------------------------------
__global__ void scatter_kernel(const int*   __restrict__ row,
                               const int*   __restrict__ col,
                               const float* __restrict__ val,
                               int*         __restrict__ cursor,
                               int2*        __restrict__ colval) {
    int stride = gridDim.x * blockDim.x;
    for (int e = blockIdx.x * blockDim.x + threadIdx.x; e < N_EDGES; e += stride) {
        int r = row[e];
        int pos = atomicAdd(&cursor[r], 1);
        colval[pos] = make_int2(col[e], __float_as_int(val[e]));
    }
}

// ---------------------------------------------------------------------------
// CSR SpMM, atomic-free: 16 lanes per row, lane q owns dims [4q, 4q+4).
// y[r] = sum_e val*x[col];  acc[r] += y[r] fused.  storeY=0 skips y write.
// ---------------------------------------------------------------------------
__global__ void spmm_csr_kernel(const int*  __restrict__ rp,
                                const int2* __restrict__ cv,
                                const float* __restrict__ x,
                                float*       __restrict__ y,
                                float*       __restrict__ acc,
                                int storeY) {
    int g = (blockIdx.x * blockDim.x + threadIdx.x) >> 4;   // row
    if (g >= N_NODES) return;
    int q = threadIdx.x & 15;
    int beg = rp[g];
    int end = rp[g + 1];
    const float4* x4 = (const float4*)x;

    float4 s = make_float4(0.f, 0.f, 0.f, 0.f);
    int i = beg;
    for (; i + 4 <= end; i += 4) {                 // 4 gathers in flight
        int2 c0 = cv[i], c1 = cv[i + 1], c2 = cv[i + 2], c3 = cv[i + 3];
        float4 g0 = x4[(size_t)c0.x * 16 + q];
        float4 g1 = x4[(size_t)c1.x * 16 + q];
        float4 g2 = x4[(size_t)c2.x * 16 + q];
        float4 g3 = x4[(size_t)c3.x * 16 + q];
        float v0 = __int_as_float(c0.y), v1 = __int_as_float(c1.y);
        float v2 = __int_as_float(c2.y), v3 = __int_as_float(c3.y);
        s.x += g0.x * v0; s.y += g0.y * v0; s.z += g0.z * v0; s.w += g0.w * v0;
        s.x += g1.x * v1; s.y += g1.y * v1; s.z += g1.z * v1; s.w += g1.w * v1;
        s.x += g2.x * v2; s.y += g2.y * v2; s.z += g2.z * v2; s.w += g2.w * v2;
        s.x += g3.x * v3; s.y += g3.y * v3; s.z += g3.z * v3; s.w += g3.w * v3;
    }
    for (; i < end; ++i) {
        int2 cc = cv[i];
        float4 gg = x4[(size_t)cc.x * 16 + q];
        float v  = __int_as_float(cc.y);
        s.x += gg.x * v; s.y += gg.y * v; s.z += gg.z * v; s.w += gg.w * v;
    }

    size_t o = (size_t)g * 16 + q;
    float4 a = ((const float4*)acc)[o];
    a.x += s.x; a.y += s.y; a.z += s.z; a.w += s.w;
    ((float4*)acc)[o] = a;
    if (storeY) ((float4*)y)[o] = s;
}

// ---------------------------------------------------------------------------
// Fallback path (R0): COO atomic SpMM + acc add
// ---------------------------------------------------------------------------
__global__ void spmm_atomic_kernel(const int*   __restrict__ row,
                                   const int*   __restrict__ col,
                                   const float* __restrict__ val,
                                   const float* __restrict__ x,
                                   float*       __restrict__ y) {
    const int total = N_EDGES * 16;
    int stride = gridDim.x * blockDim.x;
    for (int t = blockIdx.x * blockDim.x + threadIdx.x; t < total; t += stride) {
        int e = t >> 4;
        int q = t & 15;
        int r = row[e];
        int c = col[e];
        float v = val[e];
        float4 g = ((const float4*)x)[c * 16 + q];
        float* yp = y + r * 64 + q * 4;
        atomicAdd(yp + 0, g.x * v);
        atomicAdd(yp + 1, g.y * v);
        atomicAdd(yp + 2, g.z * v);
        atomicAdd(yp + 3, g.w * v);
    }
}

__global__ void acc_add_kernel(float* __restrict__ acc,
                               const float* __restrict__ add,
                               int n4) {
    int stride = gridDim.x * blockDim.x;
    for (int i = blockIdx.x * blockDim.x + threadIdx.x; i < n4; i += stride) {
        float4 a = ((const float4*)acc)[i];
        float4 b = ((const float4*)add)[i];
        a.x += b.x; a.y += b.y; a.z += b.z; a.w += b.w;
        ((float4*)acc)[i] = a;
    }
}

extern "C" void kernel_launch(void* const* d_in, const int* in_sizes, int n_in,
                              void* d_out, int out_size, void* d_ws, size_t ws_size,
                              hipStream_t stream) {
    const float* uEmb = (const float*)d_in[0];
    const float* iEmb = (const float*)d_in[1];
    const int*   row  = (const int*)  d_in[2];
    const int*   col  = (const int*)  d_in[3];
    const float* val  = (const float*)d_in[4];

    float* acc = (float*)d_out;

    const int n4total = N_NODES * (LATDIM / 4);
    const int n4u     = USER_N  * (LATDIM / 4);
    const size_t embBytes = (size_t)N_NODES * LATDIM * sizeof(float);

    const int BLK = 256;
    const int GRID_MEM = 2048;

    // ---- workspace layout ----
    auto align256 = [](size_t x) { return (x + 255) & ~(size_t)255; };
    size_t off = 0;
    size_t o_cur     = off; off += align256(embBytes);
    size_t o_nxt     = off; off += align256(embBytes);
    size_t o_colval  = off; off += align256((size_t)N_EDGES * 8);
    size_t o_rowptr  = off; off += align256(((size_t)N_NODES + 1) * 4);
    size_t o_cursor  = off; off += align256(((size_t)N_NODES + 1) * 4);
    size_t o_counts  = off; off += align256((size_t)N_NODES * 4);
    size_t o_csum    = off; off += align256((size_t)N_CHUNKS * 4);
    size_t o_coff    = off; off += align256((size_t)N_CHUNKS * 4);
    size_t needed = off;

    char* wsb = (char*)d_ws;
    float* cur0 = (float*)(wsb + o_cur);
    float* nxt0 = (float*)(wsb + o_nxt);

    if (ws_size >= needed) {
        // ================= CSR path =================
        int2* colval   = (int2*)(wsb + o_colval);
        int*  rowPtr   = (int*) (wsb + o_rowptr);
        int*  cursor   = (int*) (wsb + o_cursor);
        int*  counts   = (int*) (wsb + o_counts);
        int*  chunkSum = (int*) (wsb + o_csum);
        int*  chunkOff = (int*) (wsb + o_coff);

        // embeds -> cur, acc (runs while CSR build proceeds on same stream)
        copy_concat_kernel<<<GRID_MEM, BLK, 0, stream>>>(uEmb, iEmb, cur0, acc,
                                                         n4u, n4total);

        // build CSR once
        hipMemsetAsync(counts, 0, (size_t)N_NODES * 4, stream);
        hist_kernel<<<GRID_MEM, BLK, 0, stream>>>(row, counts);
        chunk_sum_kernel<<<N_CHUNKS, 256, 0, stream>>>(counts, chunkSum);
        scan_chunks_kernel<<<1, 1024, 0, stream>>>(chunkSum, chunkOff,
                                                   rowPtr + N_NODES);
        scan_within_kernel<<<N_CHUNKS, SCAN_CHUNK, 0, stream>>>(counts, chunkOff,
                                                                rowPtr, cursor);
        scatter_kernel<<<GRID_MEM, BLK, 0, stream>>>(row, col, val, cursor, colval);

        // 3 layers, atomic-free
        const int GRID_SPMM = (N_NODES * 16 + BLK - 1) / BLK;   // 18750
        float* cur = cur0;
        float* nxt = nxt0;
        for (int l = 0; l < N_LAYERS; ++l) {
            int storeY = (l != N_LAYERS - 1);
            spmm_csr_kernel<<<GRID_SPMM, BLK, 0, stream>>>(rowPtr, colval, cur,
                                                           nxt, acc, storeY);
            float* t = cur; cur = nxt; nxt = t;
        }
    } else {
        // ================= fallback: R0 atomic path =================
        copy_concat_kernel<<<GRID_MEM, BLK, 0, stream>>>(uEmb, iEmb, cur0, acc,
                                                         n4u, n4total);
        float* cur = cur0;
        float* nxt = nxt0;
        for (int l = 0; l < N_LAYERS; ++l) {
            hipMemsetAsync(nxt, 0, embBytes, stream);
            spmm_atomic_kernel<<<4096, BLK, 0, stream>>>(row, col, val, cur, nxt);
            acc_add_kernel<<<GRID_MEM, BLK, 0, stream>>>(acc, nxt, n4total);
            float* t = cur; cur = nxt; nxt = t;
        }
    }
}